// Round 1
// baseline (2928.532 us; speedup 1.0000x reference)
//
#include <hip/hip_runtime.h>

#define NN 50000
#define NE 800000
#define HID 256
#define HALF 128

// ---------------- deg init: deg[n] = 1.0 (self loop weight) ----------------
__global__ __launch_bounds__(256) void k_init_deg(float* __restrict__ deg) {
    int n = blockIdx.x * 256 + threadIdx.x;
    if (n < NN) deg[n] = 1.0f;
}

// ---------------- edge MLP: w[e] = sigmoid(silu(ea@W1+b1)@W2+b2); deg[col]+=w
__global__ __launch_bounds__(256) void k_edge_mlp(
    const float* __restrict__ ea, const int* __restrict__ eidx,
    const float* __restrict__ W1, const float* __restrict__ b1,
    const float* __restrict__ W2, const float* __restrict__ b2,
    float* __restrict__ w, float* __restrict__ deg) {
    int e = blockIdx.x * 256 + threadIdx.x;
    if (e >= NE) return;
    float a0 = ea[3 * e], a1 = ea[3 * e + 1], a2 = ea[3 * e + 2];
    float acc = b2[0];
#pragma unroll 8
    for (int j = 0; j < HALF; ++j) {
        float t = fmaf(a0, W1[j], fmaf(a1, W1[HALF + j], fmaf(a2, W1[2 * HALF + j], b1[j])));
        float s = t / (1.0f + __expf(-t));   // silu
        acc = fmaf(s, W2[j], acc);
    }
    float wv = 1.0f / (1.0f + __expf(-acc)); // sigmoid
    w[e] = wv;
    atomicAdd(&deg[eidx[NE + e]], wv);       // target-side degree
}

// ---------------- dinv = rsqrt(deg) ----------------
__global__ __launch_bounds__(256) void k_dinv(const float* __restrict__ deg,
                                              float* __restrict__ dinv) {
    int n = blockIdx.x * 256 + threadIdx.x;
    if (n < NN) {
        float d = deg[n];
        dinv[n] = d > 0.0f ? rsqrtf(d) : 0.0f;
    }
}

// ---------------- x = h @ Wc  (fp32 vector GEMM, 64x64 tile, BK=16) --------
__global__ __launch_bounds__(256) void k_gemm(const float* __restrict__ A,
                                              const float* __restrict__ B,
                                              float* __restrict__ C) {
    __shared__ float As[16][64]; // [k][m]
    __shared__ float Bs[16][64]; // [k][n]
    int tid = threadIdx.x;
    int tx = tid & 15;           // n-group
    int ty = tid >> 4;           // m-group
    int rowBase = blockIdx.y * 64;
    int colBase = blockIdx.x * 64;
    float acc[4][4] = {};
    int la_row = tid >> 2;        // 0..63
    int la_col = (tid & 3) * 4;   // 0,4,8,12
    int lb_row = tid >> 4;        // 0..15
    int lb_col = (tid & 15) * 4;  // 0..60
    int aRow = rowBase + la_row;
    if (aRow >= NN) aRow = NN - 1; // clamp: garbage only pollutes OOB C rows

    for (int k0 = 0; k0 < 256; k0 += 16) {
        float4 av = *(const float4*)&A[aRow * 256 + k0 + la_col];
        float4 bv = *(const float4*)&B[(k0 + lb_row) * 256 + colBase + lb_col];
        __syncthreads();
        As[la_col + 0][la_row] = av.x;
        As[la_col + 1][la_row] = av.y;
        As[la_col + 2][la_row] = av.z;
        As[la_col + 3][la_row] = av.w;
        *(float4*)&Bs[lb_row][lb_col] = bv;
        __syncthreads();
#pragma unroll
        for (int k = 0; k < 16; ++k) {
            float4 a = *(const float4*)&As[k][ty * 4];
            float4 b = *(const float4*)&Bs[k][tx * 4];
            float ar[4] = {a.x, a.y, a.z, a.w};
            float br[4] = {b.x, b.y, b.z, b.w};
#pragma unroll
            for (int i = 0; i < 4; ++i)
#pragma unroll
                for (int j = 0; j < 4; ++j)
                    acc[i][j] = fmaf(ar[i], br[j], acc[i][j]);
        }
    }
    int row0 = rowBase + ty * 4;
    int col0 = colBase + tx * 4;
#pragma unroll
    for (int i = 0; i < 4; ++i) {
        int r = row0 + i;
        if (r < NN)
            *(float4*)&C[r * 256 + col0] =
                make_float4(acc[i][0], acc[i][1], acc[i][2], acc[i][3]);
    }
}

// ---------------- out[n] = bc + x[n] * dinv[n]^2  (self loop + bias) -------
__global__ __launch_bounds__(256) void k_selfinit(
    const float* __restrict__ x, const float* __restrict__ dinv,
    const float* __restrict__ bc, float* __restrict__ out) {
    int t = blockIdx.x * 256 + threadIdx.x; // over NN*64
    int n = t >> 6;
    int c4 = (t & 63) << 2;
    if (n >= NN) return;
    float di = dinv[n];
    float s = di * di;
    float4 xv = *(const float4*)&x[n * 256 + c4];
    float4 bv = *(const float4*)&bc[c4];
    *(float4*)&out[n * 256 + c4] =
        make_float4(fmaf(xv.x, s, bv.x), fmaf(xv.y, s, bv.y),
                    fmaf(xv.z, s, bv.z), fmaf(xv.w, s, bv.w));
}

// ---------------- scatter: out[col] += x[row] * norm  (64 lanes/edge) ------
__global__ __launch_bounds__(256) void k_scatter(
    const float* __restrict__ x, const int* __restrict__ eidx,
    const float* __restrict__ w, const float* __restrict__ dinv,
    float* __restrict__ out) {
    int e = blockIdx.x * 4 + (threadIdx.x >> 6);
    int lane = threadIdx.x & 63;
    int row = eidx[e];
    int col = eidx[NE + e];
    float norm = dinv[row] * w[e] * dinv[col];
    float4 xv = *(const float4*)&x[row * 256 + lane * 4];
    float* op = &out[col * 256 + lane * 4];
    atomicAdd(op + 0, xv.x * norm);
    atomicAdd(op + 1, xv.y * norm);
    atomicAdd(op + 2, xv.z * norm);
    atomicAdd(op + 3, xv.w * norm);
}

extern "C" void kernel_launch(void* const* d_in, const int* in_sizes, int n_in,
                              void* d_out, int out_size, void* d_ws, size_t ws_size,
                              hipStream_t stream) {
    const float* h   = (const float*)d_in[0];
    const int* eidx  = (const int*)d_in[1];   // [2, NE] row-major: [0]=src, [1]=dst
    const float* ea  = (const float*)d_in[2];
    const float* W1  = (const float*)d_in[3];
    const float* b1  = (const float*)d_in[4];
    const float* W2  = (const float*)d_in[5];
    const float* b2  = (const float*)d_in[6];
    const float* Wc  = (const float*)d_in[7];
    const float* bc  = (const float*)d_in[8];
    float* out = (float*)d_out;

    // workspace layout (re-poisoned each call; everything re-initialized here)
    float* w    = (float*)d_ws;        // NE
    float* deg  = w + NE;              // NN
    float* dinv = deg + NN;            // NN
    float* x    = dinv + NN;           // NN*HID
    // total: (NE + 2*NN + NN*HID)*4 = ~54.8 MB

    k_init_deg<<<(NN + 255) / 256, 256, 0, stream>>>(deg);
    k_edge_mlp<<<(NE + 255) / 256, 256, 0, stream>>>(ea, eidx, W1, b1, W2, b2, w, deg);
    k_dinv<<<(NN + 255) / 256, 256, 0, stream>>>(deg, dinv);
    k_gemm<<<dim3(256 / 64, (NN + 63) / 64), 256, 0, stream>>>(h, Wc, x);
    k_selfinit<<<(NN * 64 + 255) / 256, 256, 0, stream>>>(x, dinv, bc, out);
    k_scatter<<<NE / 4, 256, 0, stream>>>(x, eidx, w, dinv, out);
}

// Round 2
// 670.093 us; speedup vs baseline: 4.3703x; 4.3703x over previous
//
#include <hip/hip_runtime.h>

#define NN 50000
#define NE 800000
#define HID 256
#define HALF 128

// ---------------- init: deg[n]=1.0 (self loop), cnt[n]=0 -------------------
__global__ __launch_bounds__(256) void k_init(float* __restrict__ deg,
                                              int* __restrict__ cnt) {
    int n = blockIdx.x * 256 + threadIdx.x;
    if (n < NN) { deg[n] = 1.0f; cnt[n] = 0; }
}

// ---- edge MLP: w[e]=sigmoid(silu(ea@W1+b1)@W2+b2); deg[col]+=w; cnt[col]++
__global__ __launch_bounds__(256) void k_edge_mlp(
    const float* __restrict__ ea, const int* __restrict__ eidx,
    const float* __restrict__ W1, const float* __restrict__ b1,
    const float* __restrict__ W2, const float* __restrict__ b2,
    float* __restrict__ w, float* __restrict__ deg, int* __restrict__ cnt) {
    int e = blockIdx.x * 256 + threadIdx.x;
    if (e >= NE) return;
    float a0 = ea[3 * e], a1 = ea[3 * e + 1], a2 = ea[3 * e + 2];
    float acc = b2[0];
#pragma unroll 8
    for (int j = 0; j < HALF; ++j) {
        float t = fmaf(a0, W1[j], fmaf(a1, W1[HALF + j], fmaf(a2, W1[2 * HALF + j], b1[j])));
        float s = t / (1.0f + __expf(-t));   // silu
        acc = fmaf(s, W2[j], acc);
    }
    float wv = 1.0f / (1.0f + __expf(-acc)); // sigmoid
    w[e] = wv;
    int col = eidx[NE + e];
    atomicAdd(&deg[col], wv);
    atomicAdd(&cnt[col], 1);
}

// ---------------- dinv = rsqrt(deg) ----------------
__global__ __launch_bounds__(256) void k_dinv(const float* __restrict__ deg,
                                              float* __restrict__ dinv) {
    int n = blockIdx.x * 256 + threadIdx.x;
    if (n < NN) {
        float d = deg[n];
        dinv[n] = d > 0.0f ? rsqrtf(d) : 0.0f;
    }
}

// ---------------- exclusive scan of cnt -> off[NN+1], cursor[NN] -----------
// single block, 256 threads, Hillis-Steele per 256-chunk with running carry
__global__ __launch_bounds__(256) void k_scan(const int* __restrict__ cnt,
                                              int* __restrict__ off,
                                              int* __restrict__ cursor) {
    __shared__ int smem[256];
    __shared__ int carry;
    int tid = threadIdx.x;
    if (tid == 0) carry = 0;
    __syncthreads();
    for (int base = 0; base < NN; base += 256) {
        int idx = base + tid;
        int v = (idx < NN) ? cnt[idx] : 0;
        smem[tid] = v;
        __syncthreads();
#pragma unroll
        for (int s = 1; s < 256; s <<= 1) {
            int t = (tid >= s) ? smem[tid - s] : 0;
            __syncthreads();
            smem[tid] += t;
            __syncthreads();
        }
        int excl = smem[tid] - v + carry;  // carry stable since last update
        if (idx < NN) { off[idx] = excl; cursor[idx] = excl; }
        __syncthreads();
        if (tid == 0) carry += smem[255];
        __syncthreads();
    }
    if (tid == 0) off[NN] = carry; // == NE
}

// ---------------- fill CSR: erow[p]=row, enorm[p]=dinv[row]*w*dinv[col] ----
__global__ __launch_bounds__(256) void k_fill(
    const int* __restrict__ eidx, const float* __restrict__ w,
    const float* __restrict__ dinv, int* __restrict__ cursor,
    int* __restrict__ erow, float* __restrict__ enorm) {
    int e = blockIdx.x * 256 + threadIdx.x;
    if (e >= NE) return;
    int row = eidx[e];
    int col = eidx[NE + e];
    int p = atomicAdd(&cursor[col], 1);
    erow[p] = row;
    enorm[p] = dinv[row] * w[e] * dinv[col];
}

// ---------------- x = h @ Wc  (fp32 vector GEMM, 64x64 tile, BK=16) --------
__global__ __launch_bounds__(256) void k_gemm(const float* __restrict__ A,
                                              const float* __restrict__ B,
                                              float* __restrict__ C) {
    __shared__ float As[16][64]; // [k][m]
    __shared__ float Bs[16][64]; // [k][n]
    int tid = threadIdx.x;
    int tx = tid & 15;           // n-group
    int ty = tid >> 4;           // m-group
    int rowBase = blockIdx.y * 64;
    int colBase = blockIdx.x * 64;
    float acc[4][4] = {};
    int la_row = tid >> 2;        // 0..63
    int la_col = (tid & 3) * 4;   // 0,4,8,12
    int lb_row = tid >> 4;        // 0..15
    int lb_col = (tid & 15) * 4;  // 0..60
    int aRow = rowBase + la_row;
    if (aRow >= NN) aRow = NN - 1; // clamp: garbage only pollutes OOB C rows

    for (int k0 = 0; k0 < 256; k0 += 16) {
        float4 av = *(const float4*)&A[aRow * 256 + k0 + la_col];
        float4 bv = *(const float4*)&B[(k0 + lb_row) * 256 + colBase + lb_col];
        __syncthreads();
        As[la_col + 0][la_row] = av.x;
        As[la_col + 1][la_row] = av.y;
        As[la_col + 2][la_row] = av.z;
        As[la_col + 3][la_row] = av.w;
        *(float4*)&Bs[lb_row][lb_col] = bv;
        __syncthreads();
#pragma unroll
        for (int k = 0; k < 16; ++k) {
            float4 a = *(const float4*)&As[k][ty * 4];
            float4 b = *(const float4*)&Bs[k][tx * 4];
            float ar[4] = {a.x, a.y, a.z, a.w};
            float br[4] = {b.x, b.y, b.z, b.w};
#pragma unroll
            for (int i = 0; i < 4; ++i)
#pragma unroll
                for (int j = 0; j < 4; ++j)
                    acc[i][j] = fmaf(ar[i], br[j], acc[i][j]);
        }
    }
    int row0 = rowBase + ty * 4;
    int col0 = colBase + tx * 4;
#pragma unroll
    for (int i = 0; i < 4; ++i) {
        int r = row0 + i;
        if (r < NN)
            *(float4*)&C[r * 256 + col0] =
                make_float4(acc[i][0], acc[i][1], acc[i][2], acc[i][3]);
    }
}

// ------ aggregate: one wave per node, no atomics ---------------------------
// out[n] = bc + x[n]*dinv[n]^2 + sum_{j in [off[n],off[n+1])} x[erow[j]]*enorm[j]
__global__ __launch_bounds__(256) void k_aggregate(
    const float* __restrict__ x, const int* __restrict__ off,
    const int* __restrict__ erow, const float* __restrict__ enorm,
    const float* __restrict__ dinv, const float* __restrict__ bc,
    float* __restrict__ out) {
    int n = blockIdx.x * 4 + (threadIdx.x >> 6);
    int lane = threadIdx.x & 63;
    if (n >= NN) return;
    int c4 = lane * 4;
    float di = dinv[n];
    float s = di * di;
    float4 xv = *(const float4*)&x[n * 256 + c4];
    float4 bv = *(const float4*)&bc[c4];
    float ax = fmaf(xv.x, s, bv.x);
    float ay = fmaf(xv.y, s, bv.y);
    float az = fmaf(xv.z, s, bv.z);
    float aw = fmaf(xv.w, s, bv.w);
    int jb = off[n], je = off[n + 1];
    for (int j = jb; j < je; ++j) {
        int r = erow[j];        // wave-uniform broadcast load
        float nm = enorm[j];
        float4 v = *(const float4*)&x[r * 256 + c4];
        ax = fmaf(v.x, nm, ax);
        ay = fmaf(v.y, nm, ay);
        az = fmaf(v.z, nm, az);
        aw = fmaf(v.w, nm, aw);
    }
    *(float4*)&out[n * 256 + c4] = make_float4(ax, ay, az, aw);
}

extern "C" void kernel_launch(void* const* d_in, const int* in_sizes, int n_in,
                              void* d_out, int out_size, void* d_ws, size_t ws_size,
                              hipStream_t stream) {
    const float* h   = (const float*)d_in[0];
    const int* eidx  = (const int*)d_in[1];   // [2, NE]: [0]=src(row), [1]=dst(col)
    const float* ea  = (const float*)d_in[2];
    const float* W1  = (const float*)d_in[3];
    const float* b1  = (const float*)d_in[4];
    const float* W2  = (const float*)d_in[5];
    const float* b2  = (const float*)d_in[6];
    const float* Wc  = (const float*)d_in[7];
    const float* bc  = (const float*)d_in[8];
    float* out = (float*)d_out;

    // workspace layout (~61.6 MB), fully re-initialized each call
    float* w     = (float*)d_ws;          // NE
    float* deg   = w + NE;                // NN
    float* dinv  = deg + NN;              // NN
    float* x     = dinv + NN;             // NN*HID
    int*   cnt   = (int*)(x + (size_t)NN * HID); // NN
    int*   off   = cnt + NN;              // NN+1
    int*   cursor= off + NN + 1;          // NN
    int*   erow  = cursor + NN;           // NE
    float* enorm = (float*)(erow + NE);   // NE

    k_init<<<(NN + 255) / 256, 256, 0, stream>>>(deg, cnt);
    k_edge_mlp<<<(NE + 255) / 256, 256, 0, stream>>>(ea, eidx, W1, b1, W2, b2, w, deg, cnt);
    k_dinv<<<(NN + 255) / 256, 256, 0, stream>>>(deg, dinv);
    k_scan<<<1, 256, 0, stream>>>(cnt, off, cursor);
    k_fill<<<(NE + 255) / 256, 256, 0, stream>>>(eidx, w, dinv, cursor, erow, enorm);
    k_gemm<<<dim3(256 / 64, (NN + 63) / 64), 256, 0, stream>>>(h, Wc, x);
    k_aggregate<<<(NN + 3) / 4, 256, 0, stream>>>(x, off, erow, enorm, dinv, bc, out);
}

// Round 3
// 466.473 us; speedup vs baseline: 6.2780x; 1.4365x over previous
//
#include <hip/hip_runtime.h>

#define NN 50000
#define NE 800000
#define HID 256
#define HALF 128
#define NBLK ((NN + 255) / 256)   // 196

// ---------------- init: deg[n]=1.0 (self loop), cnt[n]=0 -------------------
__global__ __launch_bounds__(256) void k_init(float* __restrict__ deg,
                                              int* __restrict__ cnt) {
    int n = blockIdx.x * 256 + threadIdx.x;
    if (n < NN) { deg[n] = 1.0f; cnt[n] = 0; }
}

// ---- edge MLP: w[e]=sigmoid(silu(ea@W1+b1)@W2+b2); deg[col]+=w; cnt[col]++
__global__ __launch_bounds__(256) void k_edge_mlp(
    const float* __restrict__ ea, const int* __restrict__ eidx,
    const float* __restrict__ W1, const float* __restrict__ b1,
    const float* __restrict__ W2, const float* __restrict__ b2,
    float* __restrict__ w, float* __restrict__ deg, int* __restrict__ cnt) {
    int e = blockIdx.x * 256 + threadIdx.x;
    if (e >= NE) return;
    float a0 = ea[3 * e], a1 = ea[3 * e + 1], a2 = ea[3 * e + 2];
    float acc = b2[0];
#pragma unroll 8
    for (int j = 0; j < HALF; ++j) {
        float t = fmaf(a0, W1[j], fmaf(a1, W1[HALF + j], fmaf(a2, W1[2 * HALF + j], b1[j])));
        float s = t / (1.0f + __expf(-t));   // silu
        acc = fmaf(s, W2[j], acc);
    }
    float wv = 1.0f / (1.0f + __expf(-acc)); // sigmoid
    w[e] = wv;
    int col = eidx[NE + e];
    atomicAdd(&deg[col], wv);
    atomicAdd(&cnt[col], 1);
}

// ---------------- dinv = rsqrt(deg) ----------------
__global__ __launch_bounds__(256) void k_dinv(const float* __restrict__ deg,
                                              float* __restrict__ dinv) {
    int n = blockIdx.x * 256 + threadIdx.x;
    if (n < NN) {
        float d = deg[n];
        dinv[n] = d > 0.0f ? rsqrtf(d) : 0.0f;
    }
}

// ---------------- 3-phase parallel exclusive scan --------------------------
// phase 1: per-block exclusive scan into off (partial), block total -> bsum
__global__ __launch_bounds__(256) void k_scan_blk(const int* __restrict__ cnt,
                                                  int* __restrict__ off,
                                                  int* __restrict__ bsum) {
    __shared__ int smem[256];
    int tid = threadIdx.x;
    int idx = blockIdx.x * 256 + tid;
    int v = (idx < NN) ? cnt[idx] : 0;
    smem[tid] = v;
    __syncthreads();
#pragma unroll
    for (int s = 1; s < 256; s <<= 1) {
        int t = (tid >= s) ? smem[tid - s] : 0;
        __syncthreads();
        smem[tid] += t;
        __syncthreads();
    }
    if (idx < NN) off[idx] = smem[tid] - v;
    if (tid == 255) bsum[blockIdx.x] = smem[255];
}

// phase 2: one block scans the NBLK block sums; off[NN] = grand total
__global__ __launch_bounds__(256) void k_scan_top(const int* __restrict__ bsum,
                                                  int* __restrict__ bpre,
                                                  int* __restrict__ off) {
    __shared__ int smem[256];
    int tid = threadIdx.x;
    int v = (tid < NBLK) ? bsum[tid] : 0;
    smem[tid] = v;
    __syncthreads();
#pragma unroll
    for (int s = 1; s < 256; s <<= 1) {
        int t = (tid >= s) ? smem[tid - s] : 0;
        __syncthreads();
        smem[tid] += t;
        __syncthreads();
    }
    if (tid < NBLK) bpre[tid] = smem[tid] - v;
    if (tid == 255) off[NN] = smem[255];   // == NE
}

// phase 3: add block prefix; off/cursor final
__global__ __launch_bounds__(256) void k_scan_add(const int* __restrict__ bpre,
                                                  int* __restrict__ off,
                                                  int* __restrict__ cursor) {
    int idx = blockIdx.x * 256 + threadIdx.x;
    if (idx < NN) {
        int o = off[idx] + bpre[blockIdx.x];
        off[idx] = o;
        cursor[idx] = o;
    }
}

// ---------------- fill CSR: erow[p]=row, enorm[p]=dinv[row]*w*dinv[col] ----
__global__ __launch_bounds__(256) void k_fill(
    const int* __restrict__ eidx, const float* __restrict__ w,
    const float* __restrict__ dinv, int* __restrict__ cursor,
    int* __restrict__ erow, float* __restrict__ enorm) {
    int e = blockIdx.x * 256 + threadIdx.x;
    if (e >= NE) return;
    int row = eidx[e];
    int col = eidx[NE + e];
    int p = atomicAdd(&cursor[col], 1);
    erow[p] = row;
    enorm[p] = dinv[row] * w[e] * dinv[col];
}

// ---------------- x = h @ Wc  (fp32 vector GEMM, 64x64 tile, BK=16) --------
__global__ __launch_bounds__(256) void k_gemm(const float* __restrict__ A,
                                              const float* __restrict__ B,
                                              float* __restrict__ C) {
    __shared__ float As[16][64]; // [k][m]
    __shared__ float Bs[16][64]; // [k][n]
    int tid = threadIdx.x;
    int tx = tid & 15;           // n-group
    int ty = tid >> 4;           // m-group
    int rowBase = blockIdx.y * 64;
    int colBase = blockIdx.x * 64;
    float acc[4][4] = {};
    int la_row = tid >> 2;        // 0..63
    int la_col = (tid & 3) * 4;   // 0,4,8,12
    int lb_row = tid >> 4;        // 0..15
    int lb_col = (tid & 15) * 4;  // 0..60
    int aRow = rowBase + la_row;
    if (aRow >= NN) aRow = NN - 1; // clamp: garbage only pollutes OOB C rows

    for (int k0 = 0; k0 < 256; k0 += 16) {
        float4 av = *(const float4*)&A[aRow * 256 + k0 + la_col];
        float4 bv = *(const float4*)&B[(k0 + lb_row) * 256 + colBase + lb_col];
        __syncthreads();
        As[la_col + 0][la_row] = av.x;
        As[la_col + 1][la_row] = av.y;
        As[la_col + 2][la_row] = av.z;
        As[la_col + 3][la_row] = av.w;
        *(float4*)&Bs[lb_row][lb_col] = bv;
        __syncthreads();
#pragma unroll
        for (int k = 0; k < 16; ++k) {
            float4 a = *(const float4*)&As[k][ty * 4];
            float4 b = *(const float4*)&Bs[k][tx * 4];
            float ar[4] = {a.x, a.y, a.z, a.w};
            float br[4] = {b.x, b.y, b.z, b.w};
#pragma unroll
            for (int i = 0; i < 4; ++i)
#pragma unroll
                for (int j = 0; j < 4; ++j)
                    acc[i][j] = fmaf(ar[i], br[j], acc[i][j]);
        }
    }
    int row0 = rowBase + ty * 4;
    int col0 = colBase + tx * 4;
#pragma unroll
    for (int i = 0; i < 4; ++i) {
        int r = row0 + i;
        if (r < NN)
            *(float4*)&C[r * 256 + col0] =
                make_float4(acc[i][0], acc[i][1], acc[i][2], acc[i][3]);
    }
}

// ------ aggregate: one wave per node, no atomics ---------------------------
// out[n] = bc + x[n]*dinv[n]^2 + sum_{j in [off[n],off[n+1])} x[erow[j]]*enorm[j]
__global__ __launch_bounds__(256) void k_aggregate(
    const float* __restrict__ x, const int* __restrict__ off,
    const int* __restrict__ erow, const float* __restrict__ enorm,
    const float* __restrict__ dinv, const float* __restrict__ bc,
    float* __restrict__ out) {
    int n = blockIdx.x * 4 + (threadIdx.x >> 6);
    int lane = threadIdx.x & 63;
    if (n >= NN) return;
    int c4 = lane * 4;
    float di = dinv[n];
    float s = di * di;
    float4 xv = *(const float4*)&x[n * 256 + c4];
    float4 bv = *(const float4*)&bc[c4];
    float ax = fmaf(xv.x, s, bv.x);
    float ay = fmaf(xv.y, s, bv.y);
    float az = fmaf(xv.z, s, bv.z);
    float aw = fmaf(xv.w, s, bv.w);
    int jb = off[n], je = off[n + 1];
    for (int j = jb; j < je; ++j) {
        int r = erow[j];        // wave-uniform broadcast load
        float nm = enorm[j];
        float4 v = *(const float4*)&x[r * 256 + c4];
        ax = fmaf(v.x, nm, ax);
        ay = fmaf(v.y, nm, ay);
        az = fmaf(v.z, nm, az);
        aw = fmaf(v.w, nm, aw);
    }
    *(float4*)&out[n * 256 + c4] = make_float4(ax, ay, az, aw);
}

extern "C" void kernel_launch(void* const* d_in, const int* in_sizes, int n_in,
                              void* d_out, int out_size, void* d_ws, size_t ws_size,
                              hipStream_t stream) {
    const float* h   = (const float*)d_in[0];
    const int* eidx  = (const int*)d_in[1];   // [2, NE]: [0]=src(row), [1]=dst(col)
    const float* ea  = (const float*)d_in[2];
    const float* W1  = (const float*)d_in[3];
    const float* b1  = (const float*)d_in[4];
    const float* W2  = (const float*)d_in[5];
    const float* b2  = (const float*)d_in[6];
    const float* Wc  = (const float*)d_in[7];
    const float* bc  = (const float*)d_in[8];
    float* out = (float*)d_out;

    // workspace layout (~61.8 MB), fully re-initialized each call
    float* w     = (float*)d_ws;          // NE
    float* deg   = w + NE;                // NN
    float* dinv  = deg + NN;              // NN
    float* x     = dinv + NN;             // NN*HID
    int*   cnt   = (int*)(x + (size_t)NN * HID); // NN
    int*   off   = cnt + NN;              // NN+1
    int*   cursor= off + NN + 1;          // NN
    int*   erow  = cursor + NN;           // NE
    float* enorm = (float*)(erow + NE);   // NE
    int*   bsum  = (int*)(enorm + NE);    // NBLK
    int*   bpre  = bsum + NBLK;           // NBLK

    k_init<<<(NN + 255) / 256, 256, 0, stream>>>(deg, cnt);
    k_edge_mlp<<<(NE + 255) / 256, 256, 0, stream>>>(ea, eidx, W1, b1, W2, b2, w, deg, cnt);
    k_dinv<<<(NN + 255) / 256, 256, 0, stream>>>(deg, dinv);
    k_scan_blk<<<NBLK, 256, 0, stream>>>(cnt, off, bsum);
    k_scan_top<<<1, 256, 0, stream>>>(bsum, bpre, off);
    k_scan_add<<<NBLK, 256, 0, stream>>>(bpre, off, cursor);
    k_fill<<<(NE + 255) / 256, 256, 0, stream>>>(eidx, w, dinv, cursor, erow, enorm);
    k_gemm<<<dim3(256 / 64, (NN + 63) / 64), 256, 0, stream>>>(h, Wc, x);
    k_aggregate<<<(NN + 3) / 4, 256, 0, stream>>>(x, off, erow, enorm, dinv, bc, out);
}

// Round 4
// 373.072 us; speedup vs baseline: 7.8498x; 1.2504x over previous
//
#include <hip/hip_runtime.h>

#define NN 50000
#define NE 800000
#define HID 256
#define HALF 128
#define NBLK ((NN + 255) / 256)   // 196
#define MT ((NN + 63) / 64)       // 782 GEMM m-tiles

typedef __attribute__((ext_vector_type(8))) short short8;   // bf16x8 frag (4 VGPR)
typedef __attribute__((ext_vector_type(4))) float floatx4;  // fp32 acc frag

// fp32 -> bf16 round-nearest-even (finite inputs)
__device__ inline unsigned short f2b(float f) {
    unsigned int u = __float_as_uint(f);
    unsigned int r = (u + 0x7FFFu + ((u >> 16) & 1u)) >> 16;
    return (unsigned short)r;
}
// bf16 bits -> fp32 (exact)
__device__ inline float b2f(unsigned short u) {
    return __uint_as_float(((unsigned int)u) << 16);
}

// ---------------- init: deg[n]=1.0 (self loop), cnt[n]=0 -------------------
__global__ __launch_bounds__(256) void k_init(float* __restrict__ deg,
                                              int* __restrict__ cnt) {
    int n = blockIdx.x * 256 + threadIdx.x;
    if (n < NN) { deg[n] = 1.0f; cnt[n] = 0; }
}

// ---------------- Wt[n][k] = bf16(Wc[k][n])  (256x256, tiny) ---------------
__global__ __launch_bounds__(256) void k_convW(const float* __restrict__ Wc,
                                               unsigned short* __restrict__ Wt) {
    int t = blockIdx.x * 256 + threadIdx.x;   // 65536
    int n = t >> 8, k = t & 255;
    Wt[n * 256 + k] = f2b(Wc[k * 256 + n]);
}

// ---- edge MLP: w[e]=sigmoid(silu(ea@W1+b1)@W2+b2); deg[col]+=w; cnt[col]++
__global__ __launch_bounds__(256) void k_edge_mlp(
    const float* __restrict__ ea, const int* __restrict__ eidx,
    const float* __restrict__ W1, const float* __restrict__ b1,
    const float* __restrict__ W2, const float* __restrict__ b2,
    float* __restrict__ w, float* __restrict__ deg, int* __restrict__ cnt) {
    int e = blockIdx.x * 256 + threadIdx.x;
    if (e >= NE) return;
    float a0 = ea[3 * e], a1 = ea[3 * e + 1], a2 = ea[3 * e + 2];
    float acc = b2[0];
#pragma unroll 8
    for (int j = 0; j < HALF; ++j) {
        float t = fmaf(a0, W1[j], fmaf(a1, W1[HALF + j], fmaf(a2, W1[2 * HALF + j], b1[j])));
        float s = t / (1.0f + __expf(-t));   // silu
        acc = fmaf(s, W2[j], acc);
    }
    float wv = 1.0f / (1.0f + __expf(-acc)); // sigmoid
    w[e] = wv;
    int col = eidx[NE + e];
    atomicAdd(&deg[col], wv);
    atomicAdd(&cnt[col], 1);
}

// ---------------- dinv = rsqrt(deg) ----------------
__global__ __launch_bounds__(256) void k_dinv(const float* __restrict__ deg,
                                              float* __restrict__ dinv) {
    int n = blockIdx.x * 256 + threadIdx.x;
    if (n < NN) {
        float d = deg[n];
        dinv[n] = d > 0.0f ? rsqrtf(d) : 0.0f;
    }
}

// ---------------- 3-phase parallel exclusive scan --------------------------
__global__ __launch_bounds__(256) void k_scan_blk(const int* __restrict__ cnt,
                                                  int* __restrict__ off,
                                                  int* __restrict__ bsum) {
    __shared__ int smem[256];
    int tid = threadIdx.x;
    int idx = blockIdx.x * 256 + tid;
    int v = (idx < NN) ? cnt[idx] : 0;
    smem[tid] = v;
    __syncthreads();
#pragma unroll
    for (int s = 1; s < 256; s <<= 1) {
        int t = (tid >= s) ? smem[tid - s] : 0;
        __syncthreads();
        smem[tid] += t;
        __syncthreads();
    }
    if (idx < NN) off[idx] = smem[tid] - v;
    if (tid == 255) bsum[blockIdx.x] = smem[255];
}

__global__ __launch_bounds__(256) void k_scan_top(const int* __restrict__ bsum,
                                                  int* __restrict__ bpre,
                                                  int* __restrict__ off) {
    __shared__ int smem[256];
    int tid = threadIdx.x;
    int v = (tid < NBLK) ? bsum[tid] : 0;
    smem[tid] = v;
    __syncthreads();
#pragma unroll
    for (int s = 1; s < 256; s <<= 1) {
        int t = (tid >= s) ? smem[tid - s] : 0;
        __syncthreads();
        smem[tid] += t;
        __syncthreads();
    }
    if (tid < NBLK) bpre[tid] = smem[tid] - v;
    if (tid == 255) off[NN] = smem[255];   // == NE
}

__global__ __launch_bounds__(256) void k_scan_add(const int* __restrict__ bpre,
                                                  int* __restrict__ off,
                                                  int* __restrict__ cursor) {
    int idx = blockIdx.x * 256 + threadIdx.x;
    if (idx < NN) {
        int o = off[idx] + bpre[blockIdx.x];
        off[idx] = o;
        cursor[idx] = o;
    }
}

// ------- fill CSR: epack[p] = {row, bits(dinv[row]*w*dinv[col])} -----------
__global__ __launch_bounds__(256) void k_fill(
    const int* __restrict__ eidx, const float* __restrict__ w,
    const float* __restrict__ dinv, int* __restrict__ cursor,
    int2* __restrict__ epack) {
    int e = blockIdx.x * 256 + threadIdx.x;
    if (e >= NE) return;
    int row = eidx[e];
    int col = eidx[NE + e];
    int p = atomicAdd(&cursor[col], 1);
    float nm = dinv[row] * w[e] * dinv[col];
    epack[p] = make_int2(row, __float_as_int(nm));
}

// ------- xh = bf16(h @ Wc) via MFMA 16x16x32 -------------------------------
// block: 256 thr = 4 waves; tile M=64 x N=256 (wave w: cols w*64..+63)
// A staged fp32->bf16 in LDS (pitch 40 ushort = 80B: 16B-aligned, 2-way banks)
// B frags loaded directly from Wt[n][k] bf16 (128 KB, L2-resident)
__global__ __launch_bounds__(256) void k_gemm_mfma(
    const float* __restrict__ A, const unsigned short* __restrict__ Wt,
    unsigned short* __restrict__ xh) {
    __shared__ __align__(16) unsigned short As[64][40];
    int tid = threadIdx.x;
    int wave = tid >> 6, lane = tid & 63;
    int mbase = blockIdx.x * 64;
    int nbase = wave * 64;
    int lrow = lane & 15;    // frag row/col within 16x16 tile
    int lg = lane >> 4;      // k-group (0..3): k = lg*8 + i
    floatx4 acc[4][4];
#pragma unroll
    for (int t = 0; t < 4; ++t)
#pragma unroll
        for (int u = 0; u < 4; ++u)
            acc[t][u] = (floatx4){0.f, 0.f, 0.f, 0.f};

    int srow = tid >> 2;     // 0..63 staging row
    int skg = tid & 3;       // k-group of 8
    int arow = mbase + srow;
    if (arow >= NN) arow = NN - 1;   // clamp: pollutes only OOB C rows

    for (int k0 = 0; k0 < 256; k0 += 32) {
        float4 f0 = *(const float4*)&A[arow * 256 + k0 + skg * 8];
        float4 f1 = *(const float4*)&A[arow * 256 + k0 + skg * 8 + 4];
        __syncthreads();   // previous iter's frag reads done
        uint4 pk;
        pk.x = (unsigned)f2b(f0.x) | ((unsigned)f2b(f0.y) << 16);
        pk.y = (unsigned)f2b(f0.z) | ((unsigned)f2b(f0.w) << 16);
        pk.z = (unsigned)f2b(f1.x) | ((unsigned)f2b(f1.y) << 16);
        pk.w = (unsigned)f2b(f1.z) | ((unsigned)f2b(f1.w) << 16);
        *(uint4*)&As[srow][skg * 8] = pk;
        __syncthreads();

        short8 af[4], bf[4];
#pragma unroll
        for (int t = 0; t < 4; ++t)
            af[t] = *(const short8*)&As[t * 16 + lrow][lg * 8];
#pragma unroll
        for (int u = 0; u < 4; ++u)
            bf[u] = *(const short8*)&Wt[(nbase + u * 16 + lrow) * 256 + k0 + lg * 8];
#pragma unroll
        for (int t = 0; t < 4; ++t)
#pragma unroll
            for (int u = 0; u < 4; ++u)
                acc[t][u] = __builtin_amdgcn_mfma_f32_16x16x32_bf16(
                    af[t], bf[u], acc[t][u], 0, 0, 0);
    }
    // C/D layout (m89-verified): col = lane&15, row = (lane>>4)*4 + reg
#pragma unroll
    for (int t = 0; t < 4; ++t) {
        int rowb = mbase + t * 16 + lg * 4;
#pragma unroll
        for (int r = 0; r < 4; ++r) {
            int row = rowb + r;
            if (row < NN) {
#pragma unroll
                for (int u = 0; u < 4; ++u)
                    xh[row * 256 + nbase + u * 16 + lrow] = f2b(acc[t][u][r]);
            }
        }
    }
}

// ------ aggregate: one wave per node, bf16 gather, no atomics --------------
// out[n] = bc + xh[n]*dinv^2 + sum_j xh[row_j]*norm_j
__global__ __launch_bounds__(256) void k_aggregate(
    const unsigned short* __restrict__ xh, const int* __restrict__ off,
    const int2* __restrict__ epack, const float* __restrict__ dinv,
    const float* __restrict__ bc, float* __restrict__ out) {
    int n = blockIdx.x * 4 + (threadIdx.x >> 6);
    int lane = threadIdx.x & 63;
    if (n >= NN) return;
    int c4 = lane * 4;
    float di = dinv[n];
    float s = di * di;
    ushort4 xv = *(const ushort4*)&xh[n * 256 + c4];
    float4 bv = *(const float4*)&bc[c4];
    float ax = fmaf(b2f(xv.x), s, bv.x);
    float ay = fmaf(b2f(xv.y), s, bv.y);
    float az = fmaf(b2f(xv.z), s, bv.z);
    float aw = fmaf(b2f(xv.w), s, bv.w);
    int jb = off[n], je = off[n + 1];
    for (int j = jb; j < je; ++j) {
        int2 ep = epack[j];
        float nm = __int_as_float(ep.y);
        ushort4 v = *(const ushort4*)&xh[ep.x * 256 + c4];
        ax = fmaf(b2f(v.x), nm, ax);
        ay = fmaf(b2f(v.y), nm, ay);
        az = fmaf(b2f(v.z), nm, az);
        aw = fmaf(b2f(v.w), nm, aw);
    }
    *(float4*)&out[n * 256 + c4] = make_float4(ax, ay, az, aw);
}

extern "C" void kernel_launch(void* const* d_in, const int* in_sizes, int n_in,
                              void* d_out, int out_size, void* d_ws, size_t ws_size,
                              hipStream_t stream) {
    const float* h   = (const float*)d_in[0];
    const int* eidx  = (const int*)d_in[1];   // [2, NE]: [0]=src(row), [1]=dst(col)
    const float* ea  = (const float*)d_in[2];
    const float* W1  = (const float*)d_in[3];
    const float* b1  = (const float*)d_in[4];
    const float* W2  = (const float*)d_in[5];
    const float* b2  = (const float*)d_in[6];
    const float* Wc  = (const float*)d_in[7];
    const float* bc  = (const float*)d_in[8];
    float* out = (float*)d_out;

    // workspace layout (~36.4 MB), all offsets 8B-aligned, re-inited each call
    char* p = (char*)d_ws;
    float* w            = (float*)p;          p += (size_t)NE * 4;
    float* deg          = (float*)p;          p += (size_t)NN * 4;
    float* dinv         = (float*)p;          p += (size_t)NN * 4;
    unsigned short* xh  = (unsigned short*)p; p += (size_t)NN * HID * 2;
    unsigned short* Wt  = (unsigned short*)p; p += (size_t)HID * HID * 2;
    int* cnt            = (int*)p;            p += (size_t)NN * 4;
    int* off            = (int*)p;            p += (size_t)(NN + 2) * 4;
    int* cursor         = (int*)p;            p += (size_t)NN * 4;
    int2* epack         = (int2*)p;           p += (size_t)NE * 8;
    int* bsum           = (int*)p;            p += (size_t)NBLK * 4;
    int* bpre           = (int*)p;

    k_init<<<(NN + 255) / 256, 256, 0, stream>>>(deg, cnt);
    k_convW<<<(HID * HID) / 256, 256, 0, stream>>>(Wc, Wt);
    k_edge_mlp<<<(NE + 255) / 256, 256, 0, stream>>>(ea, eidx, W1, b1, W2, b2, w, deg, cnt);
    k_dinv<<<(NN + 255) / 256, 256, 0, stream>>>(deg, dinv);
    k_scan_blk<<<NBLK, 256, 0, stream>>>(cnt, off, bsum);
    k_scan_top<<<1, 256, 0, stream>>>(bsum, bpre, off);
    k_scan_add<<<NBLK, 256, 0, stream>>>(bpre, off, cursor);
    k_fill<<<(NE + 255) / 256, 256, 0, stream>>>(eidx, w, dinv, cursor, epack);
    k_gemm_mfma<<<MT, 256, 0, stream>>>(h, Wt, xh);
    k_aggregate<<<(NN + 3) / 4, 256, 0, stream>>>(xh, off, epack, dinv, bc, out);
}

// Round 5
// 330.744 us; speedup vs baseline: 8.8544x; 1.1280x over previous
//
#include <hip/hip_runtime.h>

#define NN 50000
#define NE 800000
#define HID 256
#define HALF 128
#define NBLK ((NN + 255) / 256)   // 196
#define MT ((NN + 63) / 64)       // 782 GEMM m-tiles

typedef __attribute__((ext_vector_type(8))) short short8;   // bf16x8 frag (4 VGPR)
typedef __attribute__((ext_vector_type(4))) float floatx4;  // fp32 acc frag

// fp32 -> bf16 round-nearest-even (finite inputs)
__device__ inline unsigned short f2b(float f) {
    unsigned int u = __float_as_uint(f);
    unsigned int r = (u + 0x7FFFu + ((u >> 16) & 1u)) >> 16;
    return (unsigned short)r;
}
// bf16 bits -> fp32 (exact)
__device__ inline float b2f(unsigned short u) {
    return __uint_as_float(((unsigned int)u) << 16);
}

// ---------------- init: degq[n]=0 (packed {cnt:16 | sum_q48}) --------------
__global__ __launch_bounds__(256) void k_init(unsigned long long* __restrict__ degq) {
    int n = blockIdx.x * 256 + threadIdx.x;
    if (n < NN) degq[n] = 0ull;
}

// ---------------- Wt[n][k] = bf16(Wc[k][n])  (256x256, tiny) ---------------
__global__ __launch_bounds__(256) void k_convW(const float* __restrict__ Wc,
                                               unsigned short* __restrict__ Wt) {
    int t = blockIdx.x * 256 + threadIdx.x;   // 65536
    int n = t >> 8, k = t & 255;
    Wt[n * 256 + k] = f2b(Wc[k * 256 + n]);
}

// ---- edge MLP: w[e]=sigmoid(silu(ea@W1+b1)@W2+b2); degq[col] += {1,q(w)}
// weights staged in LDS (packed float4 + W2); sigmoid via v_rcp approx
__global__ __launch_bounds__(256) void k_edge_mlp(
    const float* __restrict__ ea, const int* __restrict__ eidx,
    const float* __restrict__ W1, const float* __restrict__ b1,
    const float* __restrict__ W2, const float* __restrict__ b2,
    float* __restrict__ w, unsigned long long* __restrict__ degq) {
    __shared__ float4 wp[HALF];   // {W1[0][j], W1[1][j], W1[2][j], b1[j]}
    __shared__ float w2s[HALF];
    int tid = threadIdx.x;
    if (tid < HALF) {
        wp[tid] = make_float4(W1[tid], W1[HALF + tid], W1[2 * HALF + tid], b1[tid]);
        w2s[tid] = W2[tid];
    }
    __syncthreads();
    int e = blockIdx.x * 256 + tid;
    if (e >= NE) return;
    float a0 = ea[3 * e], a1 = ea[3 * e + 1], a2 = ea[3 * e + 2];
    float acc = b2[0];
#pragma unroll 4
    for (int j = 0; j < HALF; ++j) {
        float4 wv = wp[j];                 // LDS broadcast (uniform addr, free)
        float t = fmaf(a0, wv.x, fmaf(a1, wv.y, fmaf(a2, wv.z, wv.w)));
        float s = t * __builtin_amdgcn_rcpf(1.0f + __expf(-t));   // silu
        acc = fmaf(s, w2s[j], acc);
    }
    float wv = __builtin_amdgcn_rcpf(1.0f + __expf(-acc));        // sigmoid
    w[e] = wv;
    int col = eidx[NE + e];
    // one u64 atomic: count in [63:48], fixed-point(2^-24) weight sum in [47:0]
    unsigned long long q = (1ull << 48) |
        (unsigned long long)__float2uint_rn(wv * 16777216.0f);
    atomicAdd(&degq[col], q);
}

// ---------------- unpack: cnt[n], dinv[n] = rsqrt(1 + sum_q*2^-24) ---------
__global__ __launch_bounds__(256) void k_dinv(const unsigned long long* __restrict__ degq,
                                              float* __restrict__ dinv,
                                              int* __restrict__ cnt) {
    int n = blockIdx.x * 256 + threadIdx.x;
    if (n < NN) {
        unsigned long long q = degq[n];
        cnt[n] = (int)(q >> 48);
        float d = fmaf((float)(q & 0xFFFFFFFFFFFFull), 5.9604644775390625e-8f, 1.0f);
        dinv[n] = rsqrtf(d);   // d >= 1 always
    }
}

// ---------------- 3-phase parallel exclusive scan --------------------------
__global__ __launch_bounds__(256) void k_scan_blk(const int* __restrict__ cnt,
                                                  int* __restrict__ off,
                                                  int* __restrict__ bsum) {
    __shared__ int smem[256];
    int tid = threadIdx.x;
    int idx = blockIdx.x * 256 + tid;
    int v = (idx < NN) ? cnt[idx] : 0;
    smem[tid] = v;
    __syncthreads();
#pragma unroll
    for (int s = 1; s < 256; s <<= 1) {
        int t = (tid >= s) ? smem[tid - s] : 0;
        __syncthreads();
        smem[tid] += t;
        __syncthreads();
    }
    if (idx < NN) off[idx] = smem[tid] - v;
    if (tid == 255) bsum[blockIdx.x] = smem[255];
}

__global__ __launch_bounds__(256) void k_scan_top(const int* __restrict__ bsum,
                                                  int* __restrict__ bpre,
                                                  int* __restrict__ off) {
    __shared__ int smem[256];
    int tid = threadIdx.x;
    int v = (tid < NBLK) ? bsum[tid] : 0;
    smem[tid] = v;
    __syncthreads();
#pragma unroll
    for (int s = 1; s < 256; s <<= 1) {
        int t = (tid >= s) ? smem[tid - s] : 0;
        __syncthreads();
        smem[tid] += t;
        __syncthreads();
    }
    if (tid < NBLK) bpre[tid] = smem[tid] - v;
    if (tid == 255) off[NN] = smem[255];   // == NE
}

__global__ __launch_bounds__(256) void k_scan_add(const int* __restrict__ bpre,
                                                  int* __restrict__ off,
                                                  int* __restrict__ cursor) {
    int idx = blockIdx.x * 256 + threadIdx.x;
    if (idx < NN) {
        int o = off[idx] + bpre[blockIdx.x];
        off[idx] = o;
        cursor[idx] = o;
    }
}

// ------- fill CSR: epack[p] = {row, bits(dinv[row]*w*dinv[col])} -----------
__global__ __launch_bounds__(256) void k_fill(
    const int* __restrict__ eidx, const float* __restrict__ w,
    const float* __restrict__ dinv, int* __restrict__ cursor,
    int2* __restrict__ epack) {
    int e = blockIdx.x * 256 + threadIdx.x;
    if (e >= NE) return;
    int row = eidx[e];
    int col = eidx[NE + e];
    int p = atomicAdd(&cursor[col], 1);
    float nm = dinv[row] * w[e] * dinv[col];
    epack[p] = make_int2(row, __float_as_int(nm));
}

// ------- xh = bf16(h @ Wc) via MFMA 16x16x32 -------------------------------
__global__ __launch_bounds__(256) void k_gemm_mfma(
    const float* __restrict__ A, const unsigned short* __restrict__ Wt,
    unsigned short* __restrict__ xh) {
    __shared__ __align__(16) unsigned short As[64][40];
    int tid = threadIdx.x;
    int wave = tid >> 6, lane = tid & 63;
    int mbase = blockIdx.x * 64;
    int nbase = wave * 64;
    int lrow = lane & 15;    // frag row/col within 16x16 tile
    int lg = lane >> 4;      // k-group (0..3): k = lg*8 + i
    floatx4 acc[4][4];
#pragma unroll
    for (int t = 0; t < 4; ++t)
#pragma unroll
        for (int u = 0; u < 4; ++u)
            acc[t][u] = (floatx4){0.f, 0.f, 0.f, 0.f};

    int srow = tid >> 2;     // 0..63 staging row
    int skg = tid & 3;       // k-group of 8
    int arow = mbase + srow;
    if (arow >= NN) arow = NN - 1;   // clamp: pollutes only OOB C rows

    for (int k0 = 0; k0 < 256; k0 += 32) {
        float4 f0 = *(const float4*)&A[arow * 256 + k0 + skg * 8];
        float4 f1 = *(const float4*)&A[arow * 256 + k0 + skg * 8 + 4];
        __syncthreads();   // previous iter's frag reads done
        uint4 pk;
        pk.x = (unsigned)f2b(f0.x) | ((unsigned)f2b(f0.y) << 16);
        pk.y = (unsigned)f2b(f0.z) | ((unsigned)f2b(f0.w) << 16);
        pk.z = (unsigned)f2b(f1.x) | ((unsigned)f2b(f1.y) << 16);
        pk.w = (unsigned)f2b(f1.z) | ((unsigned)f2b(f1.w) << 16);
        *(uint4*)&As[srow][skg * 8] = pk;
        __syncthreads();

        short8 af[4], bf[4];
#pragma unroll
        for (int t = 0; t < 4; ++t)
            af[t] = *(const short8*)&As[t * 16 + lrow][lg * 8];
#pragma unroll
        for (int u = 0; u < 4; ++u)
            bf[u] = *(const short8*)&Wt[(nbase + u * 16 + lrow) * 256 + k0 + lg * 8];
#pragma unroll
        for (int t = 0; t < 4; ++t)
#pragma unroll
            for (int u = 0; u < 4; ++u)
                acc[t][u] = __builtin_amdgcn_mfma_f32_16x16x32_bf16(
                    af[t], bf[u], acc[t][u], 0, 0, 0);
    }
    // C/D layout (m89-verified): col = lane&15, row = (lane>>4)*4 + reg
#pragma unroll
    for (int t = 0; t < 4; ++t) {
        int rowb = mbase + t * 16 + lg * 4;
#pragma unroll
        for (int r = 0; r < 4; ++r) {
            int row = rowb + r;
            if (row < NN) {
#pragma unroll
                for (int u = 0; u < 4; ++u)
                    xh[row * 256 + nbase + u * 16 + lrow] = f2b(acc[t][u][r]);
            }
        }
    }
}

// ------ aggregate: one wave per node, bf16 gather, no atomics --------------
__global__ __launch_bounds__(256) void k_aggregate(
    const unsigned short* __restrict__ xh, const int* __restrict__ off,
    const int2* __restrict__ epack, const float* __restrict__ dinv,
    const float* __restrict__ bc, float* __restrict__ out) {
    int n = blockIdx.x * 4 + (threadIdx.x >> 6);
    int lane = threadIdx.x & 63;
    if (n >= NN) return;
    int c4 = lane * 4;
    float di = dinv[n];
    float s = di * di;
    ushort4 xv = *(const ushort4*)&xh[n * 256 + c4];
    float4 bv = *(const float4*)&bc[c4];
    float ax = fmaf(b2f(xv.x), s, bv.x);
    float ay = fmaf(b2f(xv.y), s, bv.y);
    float az = fmaf(b2f(xv.z), s, bv.z);
    float aw = fmaf(b2f(xv.w), s, bv.w);
    int jb = off[n], je = off[n + 1];
    for (int j = jb; j < je; ++j) {
        int2 ep = epack[j];
        float nm = __int_as_float(ep.y);
        ushort4 v = *(const ushort4*)&xh[ep.x * 256 + c4];
        ax = fmaf(b2f(v.x), nm, ax);
        ay = fmaf(b2f(v.y), nm, ay);
        az = fmaf(b2f(v.z), nm, az);
        aw = fmaf(b2f(v.w), nm, aw);
    }
    *(float4*)&out[n * 256 + c4] = make_float4(ax, ay, az, aw);
}

extern "C" void kernel_launch(void* const* d_in, const int* in_sizes, int n_in,
                              void* d_out, int out_size, void* d_ws, size_t ws_size,
                              hipStream_t stream) {
    const float* h   = (const float*)d_in[0];
    const int* eidx  = (const int*)d_in[1];   // [2, NE]: [0]=src(row), [1]=dst(col)
    const float* ea  = (const float*)d_in[2];
    const float* W1  = (const float*)d_in[3];
    const float* b1  = (const float*)d_in[4];
    const float* W2  = (const float*)d_in[5];
    const float* b2  = (const float*)d_in[6];
    const float* Wc  = (const float*)d_in[7];
    const float* bc  = (const float*)d_in[8];
    float* out = (float*)d_out;

    // workspace layout (~36.6 MB), all offsets 8B-aligned, re-inited each call
    char* p = (char*)d_ws;
    float* w                 = (float*)p;              p += (size_t)NE * 4;
    unsigned long long* degq = (unsigned long long*)p; p += (size_t)NN * 8;
    float* dinv              = (float*)p;              p += (size_t)NN * 4;
    unsigned short* xh       = (unsigned short*)p;     p += (size_t)NN * HID * 2;
    unsigned short* Wt       = (unsigned short*)p;     p += (size_t)HID * HID * 2;
    int* cnt                 = (int*)p;                p += (size_t)NN * 4;
    int* off                 = (int*)p;                p += (size_t)(NN + 2) * 4;
    int* cursor              = (int*)p;                p += (size_t)NN * 4;
    int2* epack              = (int2*)p;               p += (size_t)NE * 8;
    int* bsum                = (int*)p;                p += (size_t)NBLK * 4;
    int* bpre                = (int*)p;

    k_init<<<(NN + 255) / 256, 256, 0, stream>>>(degq);
    k_convW<<<(HID * HID) / 256, 256, 0, stream>>>(Wc, Wt);
    k_edge_mlp<<<(NE + 255) / 256, 256, 0, stream>>>(ea, eidx, W1, b1, W2, b2, w, degq);
    k_dinv<<<(NN + 255) / 256, 256, 0, stream>>>(degq, dinv, cnt);
    k_scan_blk<<<NBLK, 256, 0, stream>>>(cnt, off, bsum);
    k_scan_top<<<1, 256, 0, stream>>>(bsum, bpre, off);
    k_scan_add<<<NBLK, 256, 0, stream>>>(bpre, off, cursor);
    k_fill<<<(NE + 255) / 256, 256, 0, stream>>>(eidx, w, dinv, cursor, epack);
    k_gemm_mfma<<<MT, 256, 0, stream>>>(h, Wt, xh);
    k_aggregate<<<(NN + 3) / 4, 256, 0, stream>>>(xh, off, epack, dinv, bc, out);
}

// Round 6
// 303.741 us; speedup vs baseline: 9.6416x; 1.0889x over previous
//
#include <hip/hip_runtime.h>

#define NN 50000
#define NE 800000
#define HID 256
#define HALF 128
#define NBLK ((NN + 255) / 256)   // 196
#define MT ((NN + 63) / 64)       // 782 GEMM m-tiles

typedef __attribute__((ext_vector_type(8))) short short8;   // bf16x8 frag (4 VGPR)
typedef __attribute__((ext_vector_type(4))) float floatx4;  // fp32 acc frag

// fp32 -> bf16 round-nearest-even (finite inputs)
__device__ inline unsigned short f2b(float f) {
    unsigned int u = __float_as_uint(f);
    unsigned int r = (u + 0x7FFFu + ((u >> 16) & 1u)) >> 16;
    return (unsigned short)r;
}
// bf16 bits -> fp32 (exact)
__device__ inline float b2f(unsigned int u) {
    return __uint_as_float(u << 16);
}

// ---------------- init: degq[n]=0 (packed {cnt:16 | sum_q48}) --------------
__global__ __launch_bounds__(256) void k_init(unsigned long long* __restrict__ degq) {
    int n = blockIdx.x * 256 + threadIdx.x;
    if (n < NN) degq[n] = 0ull;
}

// ---------------- Wt[n][k] = bf16(Wc[k][n])  (256x256, tiny) ---------------
__global__ __launch_bounds__(256) void k_convW(const float* __restrict__ Wc,
                                               unsigned short* __restrict__ Wt) {
    int t = blockIdx.x * 256 + threadIdx.x;   // 65536
    int n = t >> 8, k = t & 255;
    Wt[n * 256 + k] = f2b(Wc[k * 256 + n]);
}

// ---- edge MLP: w[e]=sigmoid(silu(ea@W1+b1)@W2+b2); degq[col] += {1,q(w)}
__global__ __launch_bounds__(256) void k_edge_mlp(
    const float* __restrict__ ea, const int* __restrict__ eidx,
    const float* __restrict__ W1, const float* __restrict__ b1,
    const float* __restrict__ W2, const float* __restrict__ b2,
    float* __restrict__ w, unsigned long long* __restrict__ degq) {
    __shared__ float4 wp[HALF];   // {W1[0][j], W1[1][j], W1[2][j], b1[j]}
    __shared__ float w2s[HALF];
    int tid = threadIdx.x;
    if (tid < HALF) {
        wp[tid] = make_float4(W1[tid], W1[HALF + tid], W1[2 * HALF + tid], b1[tid]);
        w2s[tid] = W2[tid];
    }
    __syncthreads();
    int e = blockIdx.x * 256 + tid;
    if (e >= NE) return;
    float a0 = ea[3 * e], a1 = ea[3 * e + 1], a2 = ea[3 * e + 2];
    float acc = b2[0];
#pragma unroll 4
    for (int j = 0; j < HALF; ++j) {
        float4 wv = wp[j];                 // LDS broadcast (uniform addr, free)
        float t = fmaf(a0, wv.x, fmaf(a1, wv.y, fmaf(a2, wv.z, wv.w)));
        float s = t * __builtin_amdgcn_rcpf(1.0f + __expf(-t));   // silu
        acc = fmaf(s, w2s[j], acc);
    }
    float wv = __builtin_amdgcn_rcpf(1.0f + __expf(-acc));        // sigmoid
    w[e] = wv;
    int col = eidx[NE + e];
    // one u64 atomic: count in [63:48], fixed-point(2^-24) weight sum in [47:0]
    unsigned long long q = (1ull << 48) |
        (unsigned long long)__float2uint_rn(wv * 16777216.0f);
    atomicAdd(&degq[col], q);
}

// ------- scan phase 1 (fused degq unpack): dinv, per-block scan, bsum ------
__global__ __launch_bounds__(256) void k_scan_blk(
    const unsigned long long* __restrict__ degq, float* __restrict__ dinv,
    int* __restrict__ off, int* __restrict__ bsum) {
    __shared__ int smem[256];
    int tid = threadIdx.x;
    int idx = blockIdx.x * 256 + tid;
    int v = 0;
    if (idx < NN) {
        unsigned long long q = degq[idx];
        v = (int)(q >> 48);
        float d = fmaf((float)(q & 0xFFFFFFFFFFFFull), 5.9604644775390625e-8f, 1.0f);
        dinv[idx] = rsqrtf(d);   // d >= 1 always
    }
    smem[tid] = v;
    __syncthreads();
#pragma unroll
    for (int s = 1; s < 256; s <<= 1) {
        int t = (tid >= s) ? smem[tid - s] : 0;
        __syncthreads();
        smem[tid] += t;
        __syncthreads();
    }
    if (idx < NN) off[idx] = smem[tid] - v;
    if (tid == 255) bsum[blockIdx.x] = smem[255];
}

__global__ __launch_bounds__(256) void k_scan_top(const int* __restrict__ bsum,
                                                  int* __restrict__ bpre,
                                                  int* __restrict__ off) {
    __shared__ int smem[256];
    int tid = threadIdx.x;
    int v = (tid < NBLK) ? bsum[tid] : 0;
    smem[tid] = v;
    __syncthreads();
#pragma unroll
    for (int s = 1; s < 256; s <<= 1) {
        int t = (tid >= s) ? smem[tid - s] : 0;
        __syncthreads();
        smem[tid] += t;
        __syncthreads();
    }
    if (tid < NBLK) bpre[tid] = smem[tid] - v;
    if (tid == 255) off[NN] = smem[255];   // == NE
}

__global__ __launch_bounds__(256) void k_scan_add(const int* __restrict__ bpre,
                                                  int* __restrict__ off,
                                                  int* __restrict__ cursor) {
    int idx = blockIdx.x * 256 + threadIdx.x;
    if (idx < NN) {
        int o = off[idx] + bpre[blockIdx.x];
        off[idx] = o;
        cursor[idx] = o;
    }
}

// --- fill CSR: epk[p] = {row:16 | bf16(dinv[row]*w*dinv[col]):16} ----------
__global__ __launch_bounds__(256) void k_fill(
    const int* __restrict__ eidx, const float* __restrict__ w,
    const float* __restrict__ dinv, int* __restrict__ cursor,
    unsigned int* __restrict__ epk) {
    int e = blockIdx.x * 256 + threadIdx.x;
    if (e >= NE) return;
    int row = eidx[e];
    int col = eidx[NE + e];
    int p = atomicAdd(&cursor[col], 1);
    float nm = dinv[row] * w[e] * dinv[col];
    epk[p] = (unsigned)row | ((unsigned)f2b(nm) << 16);
}

// ------- xh = bf16(h @ Wc) via MFMA 16x16x32 -------------------------------
__global__ __launch_bounds__(256) void k_gemm_mfma(
    const float* __restrict__ A, const unsigned short* __restrict__ Wt,
    unsigned short* __restrict__ xh) {
    __shared__ __align__(16) unsigned short As[64][40];
    int tid = threadIdx.x;
    int wave = tid >> 6, lane = tid & 63;
    int mbase = blockIdx.x * 64;
    int nbase = wave * 64;
    int lrow = lane & 15;    // frag row/col within 16x16 tile
    int lg = lane >> 4;      // k-group (0..3): k = lg*8 + i
    floatx4 acc[4][4];
#pragma unroll
    for (int t = 0; t < 4; ++t)
#pragma unroll
        for (int u = 0; u < 4; ++u)
            acc[t][u] = (floatx4){0.f, 0.f, 0.f, 0.f};

    int srow = tid >> 2;     // 0..63 staging row
    int skg = tid & 3;       // k-group of 8
    int arow = mbase + srow;
    if (arow >= NN) arow = NN - 1;   // clamp: pollutes only OOB C rows

    for (int k0 = 0; k0 < 256; k0 += 32) {
        float4 f0 = *(const float4*)&A[arow * 256 + k0 + skg * 8];
        float4 f1 = *(const float4*)&A[arow * 256 + k0 + skg * 8 + 4];
        __syncthreads();   // previous iter's frag reads done
        uint4 pk;
        pk.x = (unsigned)f2b(f0.x) | ((unsigned)f2b(f0.y) << 16);
        pk.y = (unsigned)f2b(f0.z) | ((unsigned)f2b(f0.w) << 16);
        pk.z = (unsigned)f2b(f1.x) | ((unsigned)f2b(f1.y) << 16);
        pk.w = (unsigned)f2b(f1.z) | ((unsigned)f2b(f1.w) << 16);
        *(uint4*)&As[srow][skg * 8] = pk;
        __syncthreads();

        short8 af[4], bf[4];
#pragma unroll
        for (int t = 0; t < 4; ++t)
            af[t] = *(const short8*)&As[t * 16 + lrow][lg * 8];
#pragma unroll
        for (int u = 0; u < 4; ++u)
            bf[u] = *(const short8*)&Wt[(nbase + u * 16 + lrow) * 256 + k0 + lg * 8];
#pragma unroll
        for (int t = 0; t < 4; ++t)
#pragma unroll
            for (int u = 0; u < 4; ++u)
                acc[t][u] = __builtin_amdgcn_mfma_f32_16x16x32_bf16(
                    af[t], bf[u], acc[t][u], 0, 0, 0);
    }
    // C/D layout (m89-verified): col = lane&15, row = (lane>>4)*4 + reg
#pragma unroll
    for (int t = 0; t < 4; ++t) {
        int rowb = mbase + t * 16 + lg * 4;
#pragma unroll
        for (int r = 0; r < 4; ++r) {
            int row = rowb + r;
            if (row < NN) {
#pragma unroll
                for (int u = 0; u < 4; ++u)
                    xh[row * 256 + nbase + u * 16 + lrow] = f2b(acc[t][u][r]);
            }
        }
    }
}

// ------ aggregate: one wave per node, 4-unrolled bf16 gather, no atomics ---
__global__ __launch_bounds__(256) void k_aggregate(
    const unsigned short* __restrict__ xh, const int* __restrict__ off,
    const unsigned int* __restrict__ epk, const float* __restrict__ dinv,
    const float* __restrict__ bc, float* __restrict__ out) {
    int n = blockIdx.x * 4 + (threadIdx.x >> 6);
    int lane = threadIdx.x & 63;
    if (n >= NN) return;
    int c4 = lane * 4;
    float di = dinv[n];
    float s = di * di;
    ushort4 xv = *(const ushort4*)&xh[n * 256 + c4];
    float4 bv = *(const float4*)&bc[c4];
    float ax = fmaf(b2f(xv.x), s, bv.x);
    float ay = fmaf(b2f(xv.y), s, bv.y);
    float az = fmaf(b2f(xv.z), s, bv.z);
    float aw = fmaf(b2f(xv.w), s, bv.w);
    int jb = off[n], je = off[n + 1];
    int j = jb;
    for (; j + 4 <= je; j += 4) {
        // 4 independent records -> 4 gathers in flight
        unsigned p0 = epk[j], p1 = epk[j + 1], p2 = epk[j + 2], p3 = epk[j + 3];
        ushort4 v0 = *(const ushort4*)&xh[(p0 & 0xFFFFu) * 256 + c4];
        ushort4 v1 = *(const ushort4*)&xh[(p1 & 0xFFFFu) * 256 + c4];
        ushort4 v2 = *(const ushort4*)&xh[(p2 & 0xFFFFu) * 256 + c4];
        ushort4 v3 = *(const ushort4*)&xh[(p3 & 0xFFFFu) * 256 + c4];
        float n0 = b2f(p0 >> 16), n1 = b2f(p1 >> 16);
        float n2 = b2f(p2 >> 16), n3 = b2f(p3 >> 16);
        ax = fmaf(b2f(v0.x), n0, ax); ay = fmaf(b2f(v0.y), n0, ay);
        az = fmaf(b2f(v0.z), n0, az); aw = fmaf(b2f(v0.w), n0, aw);
        ax = fmaf(b2f(v1.x), n1, ax); ay = fmaf(b2f(v1.y), n1, ay);
        az = fmaf(b2f(v1.z), n1, az); aw = fmaf(b2f(v1.w), n1, aw);
        ax = fmaf(b2f(v2.x), n2, ax); ay = fmaf(b2f(v2.y), n2, ay);
        az = fmaf(b2f(v2.z), n2, az); aw = fmaf(b2f(v2.w), n2, aw);
        ax = fmaf(b2f(v3.x), n3, ax); ay = fmaf(b2f(v3.y), n3, ay);
        az = fmaf(b2f(v3.z), n3, az); aw = fmaf(b2f(v3.w), n3, aw);
    }
    for (; j < je; ++j) {
        unsigned p = epk[j];
        float nm = b2f(p >> 16);
        ushort4 v = *(const ushort4*)&xh[(p & 0xFFFFu) * 256 + c4];
        ax = fmaf(b2f(v.x), nm, ax); ay = fmaf(b2f(v.y), nm, ay);
        az = fmaf(b2f(v.z), nm, az); aw = fmaf(b2f(v.w), nm, aw);
    }
    *(float4*)&out[n * 256 + c4] = make_float4(ax, ay, az, aw);
}

extern "C" void kernel_launch(void* const* d_in, const int* in_sizes, int n_in,
                              void* d_out, int out_size, void* d_ws, size_t ws_size,
                              hipStream_t stream) {
    const float* h   = (const float*)d_in[0];
    const int* eidx  = (const int*)d_in[1];   // [2, NE]: [0]=src(row), [1]=dst(col)
    const float* ea  = (const float*)d_in[2];
    const float* W1  = (const float*)d_in[3];
    const float* b1  = (const float*)d_in[4];
    const float* W2  = (const float*)d_in[5];
    const float* b2  = (const float*)d_in[6];
    const float* Wc  = (const float*)d_in[7];
    const float* bc  = (const float*)d_in[8];
    float* out = (float*)d_out;

    // workspace layout (~33 MB), all offsets 8B-aligned, re-inited each call
    char* p = (char*)d_ws;
    float* w                 = (float*)p;              p += (size_t)NE * 4;
    unsigned long long* degq = (unsigned long long*)p; p += (size_t)NN * 8;
    float* dinv              = (float*)p;              p += (size_t)NN * 4;
    unsigned short* xh       = (unsigned short*)p;     p += (size_t)NN * HID * 2;
    unsigned short* Wt       = (unsigned short*)p;     p += (size_t)HID * HID * 2;
    int* off                 = (int*)p;                p += (size_t)(NN + 2) * 4;
    int* cursor              = (int*)p;                p += (size_t)NN * 4;
    unsigned int* epk        = (unsigned int*)p;       p += (size_t)NE * 4;
    int* bsum                = (int*)p;                p += (size_t)NBLK * 4;
    int* bpre                = (int*)p;

    k_init<<<(NN + 255) / 256, 256, 0, stream>>>(degq);
    k_convW<<<(HID * HID) / 256, 256, 0, stream>>>(Wc, Wt);
    k_edge_mlp<<<(NE + 255) / 256, 256, 0, stream>>>(ea, eidx, W1, b1, W2, b2, w, degq);
    k_scan_blk<<<NBLK, 256, 0, stream>>>(degq, dinv, off, bsum);
    k_scan_top<<<1, 256, 0, stream>>>(bsum, bpre, off);
    k_scan_add<<<NBLK, 256, 0, stream>>>(bpre, off, cursor);
    k_fill<<<(NE + 255) / 256, 256, 0, stream>>>(eidx, w, dinv, cursor, epk);
    k_gemm_mfma<<<MT, 256, 0, stream>>>(h, Wt, xh);
    k_aggregate<<<(NN + 3) / 4, 256, 0, stream>>>(xh, off, epk, dinv, bc, out);
}